// Round 1
// baseline (1384.686 us; speedup 1.0000x reference)
//
#include <hip/hip_runtime.h>

#define T_STEPS 301
#define IN_DIM  40

// Fast activations: graceful at +/-inf (rcp(inf)=0), no NaNs.
__device__ __forceinline__ float sigm(float x) {
  return __builtin_amdgcn_rcpf(1.0f + __expf(-x));
}
__device__ __forceinline__ float tanh_fast(float x) {
  return 1.0f - 2.0f * __builtin_amdgcn_rcpf(__expf(2.0f * x) + 1.0f);
}
__device__ __forceinline__ float fc(const float4 f, int v) {
  switch (v) { case 0: return f.x; case 1: return f.y; case 2: return f.z; default: return f.w; }
}

// ws float layout:
// [0,16384)      wp_hh[j][l][c] = w_hh[(c*64+l)*64 + j]
// [16384,26624)  wip[i][l][c]   = w_ih[(c*64+l)*40 + i]
// [26624,26880)  bias[l][c]     = b_ih[c*64+l] + b_hh[c*64+l]
__global__ void lstm_prep(const float* __restrict__ w_ih, const float* __restrict__ w_hh,
                          const float* __restrict__ b_ih, const float* __restrict__ b_hh,
                          float* __restrict__ ws) {
  const int g = threadIdx.x;          // 0..255, gate id = c*64+l
  const int c = g >> 6, l = g & 63;
  for (int j = 0; j < 64; ++j)
    ws[(j * 64 + l) * 4 + c] = w_hh[g * 64 + j];
  for (int i = 0; i < IN_DIM; ++i)
    ws[16384 + (i * 64 + l) * 4 + c] = w_ih[g * IN_DIM + i];
  ws[26624 + l * 4 + c] = b_ih[g] + b_hh[g];
}

__global__ __launch_bounds__(256, 1)
void lstm_main(const float* __restrict__ x, const float* __restrict__ wsp,
               const float* __restrict__ w_clf, const float* __restrict__ b_clf,
               float* __restrict__ out) {
  extern __shared__ float smem[];     // 26624 weights + 64*20 h = 27904 floats
  float* wp  = smem;                  // [j=64][l=64][c=4]
  float* wip = smem + 16384;          // [i=40][l=64][c=4]
  float* hs  = smem + 26624;          // [j=64][20] (16 batch cols + 4 pad)

  {
    const float4* g4 = (const float4*)wsp;
    float4* s4 = (float4*)smem;
    for (int k = threadIdx.x; k < 6656; k += 256) s4[k] = g4[k];
    for (int k = threadIdx.x; k < 1280; k += 256) hs[k] = 0.0f;
  }
  __syncthreads();   // the only barrier before the epilogue

  const int tid = threadIdx.x;
  const int l  = tid & 63;            // hidden index (lane)
  const int bb = tid >> 6;            // wave id = batch group
  const int b0 = blockIdx.x * 16 + bb * 4;

  const float4 bias = *(const float4*)(wsp + 26624 + l * 4);

  const float4* xq0 = (const float4*)(x + (size_t)(b0 + 0) * T_STEPS * IN_DIM);
  const float4* xq1 = (const float4*)(x + (size_t)(b0 + 1) * T_STEPS * IN_DIM);
  const float4* xq2 = (const float4*)(x + (size_t)(b0 + 2) * T_STEPS * IN_DIM);
  const float4* xq3 = (const float4*)(x + (size_t)(b0 + 3) * T_STEPS * IN_DIM);

  float cc0 = 0.f, cc1 = 0.f, cc2 = 0.f, cc3 = 0.f;   // cell state, 4 batches @ hidden l
  float a0 = 0.f, a1 = 0.f, a2 = 0.f, a3 = 0.f;       // fused classifier accumulators

  float* hw       = hs + l * 20 + bb * 4;             // this thread's h write slot
  const float* hr = hs + bb * 4;                      // + j*20: wave-uniform h reads

  for (int t = 0; t < T_STEPS; ++t) {
    // Issue x loads early (wave-uniform rows); j-loop below hides HBM latency.
    float4 xr0[10], xr1[10], xr2[10], xr3[10];
#pragma unroll
    for (int q = 0; q < 10; ++q) {
      xr0[q] = xq0[q]; xr1[q] = xq1[q]; xr2[q] = xq2[q]; xr3[q] = xq3[q];
    }
    xq0 += 10; xq1 += 10; xq2 += 10; xq3 += 10;
    __builtin_amdgcn_sched_barrier(0);  // pin load issue before the compute

    float zi0 = bias.x, zi1 = bias.x, zi2 = bias.x, zi3 = bias.x;
    float zf0 = bias.y, zf1 = bias.y, zf2 = bias.y, zf3 = bias.y;
    float zg0 = bias.z, zg1 = bias.z, zg2 = bias.z, zg3 = bias.z;
    float zo0 = bias.w, zo1 = bias.w, zo2 = bias.w, zo3 = bias.w;

    // Recurrent part: z += h[t-1] @ w_hh^T   (h broadcast-read, w conflict-free b128)
#pragma unroll 4
    for (int j = 0; j < 64; ++j) {
      const float4 h4 = *(const float4*)(hr + j * 20);
      const float4 w4 = *(const float4*)(wp + (j * 64 + l) * 4);
      zi0 += h4.x * w4.x; zi1 += h4.y * w4.x; zi2 += h4.z * w4.x; zi3 += h4.w * w4.x;
      zf0 += h4.x * w4.y; zf1 += h4.y * w4.y; zf2 += h4.z * w4.y; zf3 += h4.w * w4.y;
      zg0 += h4.x * w4.z; zg1 += h4.y * w4.z; zg2 += h4.z * w4.z; zg3 += h4.w * w4.z;
      zo0 += h4.x * w4.w; zo1 += h4.y * w4.w; zo2 += h4.z * w4.w; zo3 += h4.w * w4.w;
    }

    // Input projection: z += x[t] @ w_ih^T
#pragma unroll
    for (int q = 0; q < 10; ++q) {
#pragma unroll
      for (int v = 0; v < 4; ++v) {
        const float4 w4 = *(const float4*)(wip + ((q * 4 + v) * 64 + l) * 4);
        const float x0 = fc(xr0[q], v), x1 = fc(xr1[q], v);
        const float x2 = fc(xr2[q], v), x3 = fc(xr3[q], v);
        zi0 += x0 * w4.x; zi1 += x1 * w4.x; zi2 += x2 * w4.x; zi3 += x3 * w4.x;
        zf0 += x0 * w4.y; zf1 += x1 * w4.y; zf2 += x2 * w4.y; zf3 += x3 * w4.y;
        zg0 += x0 * w4.z; zg1 += x1 * w4.z; zg2 += x2 * w4.z; zg3 += x3 * w4.z;
        zo0 += x0 * w4.w; zo1 += x1 * w4.w; zo2 += x2 * w4.w; zo3 += x3 * w4.w;
      }
    }

    // Gates + state update + fused classifier dot
    const float wc = w_clf[t * 64 + l];
    float h0, h1, h2, h3;
    { const float ig = sigm(zi0), fg = sigm(zf0), gg = tanh_fast(zg0), og = sigm(zo0);
      cc0 = fg * cc0 + ig * gg; h0 = og * tanh_fast(cc0); a0 += h0 * wc; }
    { const float ig = sigm(zi1), fg = sigm(zf1), gg = tanh_fast(zg1), og = sigm(zo1);
      cc1 = fg * cc1 + ig * gg; h1 = og * tanh_fast(cc1); a1 += h1 * wc; }
    { const float ig = sigm(zi2), fg = sigm(zf2), gg = tanh_fast(zg2), og = sigm(zo2);
      cc2 = fg * cc2 + ig * gg; h2 = og * tanh_fast(cc2); a2 += h2 * wc; }
    { const float ig = sigm(zi3), fg = sigm(zf3), gg = tanh_fast(zg3), og = sigm(zo3);
      cc3 = fg * cc3 + ig * gg; h3 = og * tanh_fast(cc3); a3 += h3 * wc; }

    *(float4*)hw = make_float4(h0, h1, h2, h3);
    // Wave-private ordering: ensure h write lands before next step's reads.
    asm volatile("s_waitcnt lgkmcnt(0)" ::: "memory");
  }

  // Epilogue: reduce classifier partials over hidden dim (reuse hs; cols are wave-private)
  *(float4*)hw = make_float4(a0, a1, a2, a3);
  __syncthreads();
  if (tid < 16) {
    float s = b_clf[0];
#pragma unroll
    for (int j = 0; j < 64; ++j) s += hs[j * 20 + tid];
    out[blockIdx.x * 16 + tid] = s;
  }
}

extern "C" void kernel_launch(void* const* d_in, const int* in_sizes, int n_in,
                              void* d_out, int out_size, void* d_ws, size_t ws_size,
                              hipStream_t stream) {
  const float* x     = (const float*)d_in[0];
  const float* w_ih  = (const float*)d_in[1];
  const float* w_hh  = (const float*)d_in[2];
  const float* b_ih  = (const float*)d_in[3];
  const float* b_hh  = (const float*)d_in[4];
  const float* w_clf = (const float*)d_in[5];
  const float* b_clf = (const float*)d_in[6];
  float* ws  = (float*)d_ws;
  float* out = (float*)d_out;

  lstm_prep<<<1, 256, 0, stream>>>(w_ih, w_hh, b_ih, b_hh, ws);

  const size_t shmem = 27904 * sizeof(float);  // ~109 KB dynamic LDS
  (void)hipFuncSetAttribute((const void*)lstm_main,
                            hipFuncAttributeMaxDynamicSharedMemorySize, (int)shmem);
  lstm_main<<<256, 256, shmem, stream>>>(x, ws, w_clf, b_clf, out);
}

// Round 2
// 323.615 us; speedup vs baseline: 4.2788x; 4.2788x over previous
//
#include <hip/hip_runtime.h>

#define T_STEPS 301
#define IN_DIM  40

typedef __attribute__((ext_vector_type(8))) short bf16x8;
typedef __attribute__((ext_vector_type(4))) float f32x4;
typedef unsigned short ushort_t;
typedef unsigned int uint_t;

__device__ __forceinline__ float sigm(float x) {
  return __builtin_amdgcn_rcpf(1.0f + __expf(-x));
}
__device__ __forceinline__ float tanh_fast(float x) {
  return 1.0f - 2.0f * __builtin_amdgcn_rcpf(__expf(2.0f * x) + 1.0f);
}

// Round-to-nearest bf16 of f (as ushort bits).
__device__ __forceinline__ ushort_t bf16_rn(float f) {
  uint_t u = __float_as_uint(f);
  uint_t r = u + 0x7FFFu + ((u >> 16) & 1u);
  return (ushort_t)(r >> 16);
}
// Split f into hi + lo bf16 (hi = rn(f), lo = rn(f - hi)).
__device__ __forceinline__ void split1(float f, ushort_t& hi, ushort_t& lo) {
  hi = bf16_rn(f);
  float fhi = __uint_as_float((uint_t)hi << 16);
  lo = bf16_rn(f - fhi);
}
__device__ __forceinline__ void split8(const float* v, bf16x8& hi, bf16x8& lo) {
#pragma unroll
  for (int e = 0; e < 8; ++e) {
    ushort_t h, l;
    split1(v[e], h, l);
    hi[e] = (short)h;
    lo[e] = (short)l;
  }
}

// Per block: 16 batches (M=16), 4 waves. Wave w owns hidden strip n in [16w,16w+16)
// for ALL 4 gate types -> activation is in-register (no z exchange).
// h exchanged via double-buffered LDS planes (bf16 hi/lo), chunk-XOR swizzled.
__global__ __launch_bounds__(256, 1)
void lstm_mfma(const float* __restrict__ x, const float* __restrict__ w_ih,
               const float* __restrict__ w_hh, const float* __restrict__ b_ih,
               const float* __restrict__ b_hh, const float* __restrict__ w_clf,
               const float* __restrict__ b_clf, float* __restrict__ out) {
  __shared__ ushort_t hbuf[2][2][16][64];  // [buf][hi/lo][b][8 chunks x 8 bf16], 8 KB
  __shared__ float red[64][17];            // epilogue reduce

  const int tid = threadIdx.x;
  const int l   = tid & 63;
  const int w   = tid >> 6;
  const int col = l & 15;        // A-row (batch) for frag reads; D-col (n')
  const int g16 = l >> 4;        // k-group for A/B frags; D-row group (batch/4)
  const int n   = w * 16 + col;  // this thread's hidden index within [0,64)
  const int b0  = blockIdx.x * 16;

  // ---- weight B-frags in registers: B[k][n] = W[gate_row][k] ----
  bf16x8 wh_hi[4][2], wh_lo[4][2], wi_hi[4][2], wi_lo[4][2];
#pragma unroll
  for (int c = 0; c < 4; ++c) {
    const float* wr = w_hh + (size_t)(c * 64 + n) * 64;
#pragma unroll
    for (int kc = 0; kc < 2; ++kc) {
      float v[8];
      *(float4*)&v[0] = *(const float4*)(wr + kc * 32 + g16 * 8);
      *(float4*)&v[4] = *(const float4*)(wr + kc * 32 + g16 * 8 + 4);
      split8(v, wh_hi[c][kc], wh_lo[c][kc]);
    }
    const float* wir = w_ih + (size_t)(c * 64 + n) * IN_DIM;
    {
      float v[8];  // kc=0: k=8*g16..+8 <= 31 < 40, all lanes valid
      *(float4*)&v[0] = *(const float4*)(wir + g16 * 8);
      *(float4*)&v[4] = *(const float4*)(wir + g16 * 8 + 4);
      split8(v, wi_hi[c][0], wi_lo[c][0]);
    }
    {
      float v[8] = {0, 0, 0, 0, 0, 0, 0, 0};  // kc=1: only k=32..39 real
      if (g16 == 0) {
        *(float4*)&v[0] = *(const float4*)(wir + 32);
        *(float4*)&v[4] = *(const float4*)(wir + 36);
      }
      split8(v, wi_hi[c][1], wi_lo[c][1]);
    }
  }

  float bias[4];
#pragma unroll
  for (int c = 0; c < 4; ++c) bias[c] = b_ih[c * 64 + n] + b_hh[c * 64 + n];

  // ---- zero h buffer 0 (t=0 reads h=0) ----
  {
    uint_t* hz = (uint_t*)&hbuf[0][0][0][0];
    for (int i = tid; i < 1024; i += 256) hz[i] = 0;
  }
  __syncthreads();

  float cc[4]   = {0.f, 0.f, 0.f, 0.f};
  float aclf[4] = {0.f, 0.f, 0.f, 0.f};

  // x A-frag loads: lane reads x[b0+col][t][8*g16 .. +8] (+32 for kc=1, g16==0)
  const float* xp = x + (size_t)(b0 + col) * T_STEPS * IN_DIM + g16 * 8;
  float4 xa0 = *(const float4*)(xp);
  float4 xa1 = *(const float4*)(xp + 4);
  float4 xb0 = make_float4(0.f, 0.f, 0.f, 0.f);
  float4 xb1 = make_float4(0.f, 0.f, 0.f, 0.f);
  if (g16 == 0) {
    xb0 = *(const float4*)(xp + 32);
    xb1 = *(const float4*)(xp + 36);
  }

  for (int t = 0; t < T_STEPS; ++t) {
    const int br = t & 1, bw = br ^ 1;

    // A-frags for h (hi/lo planes, swizzle-matched to the writes below)
    bf16x8 ah[2], al[2];
#pragma unroll
    for (int kc = 0; kc < 2; ++kc) {
      const int cj = (kc * 4 + g16) ^ (col & 7);
      ah[kc] = *(const bf16x8*)&hbuf[br][0][col][cj * 8];
      al[kc] = *(const bf16x8*)&hbuf[br][1][col][cj * 8];
    }

    f32x4 acc[4];
#pragma unroll
    for (int c = 0; c < 4; ++c) acc[c] = (f32x4){bias[c], bias[c], bias[c], bias[c]};

    // recurrent: z += h @ w_hh^T   (3-product split-bf16)
#pragma unroll
    for (int c = 0; c < 4; ++c) {
#pragma unroll
      for (int kc = 0; kc < 2; ++kc) {
        acc[c] = __builtin_amdgcn_mfma_f32_16x16x32_bf16(ah[kc], wh_hi[c][kc], acc[c], 0, 0, 0);
        acc[c] = __builtin_amdgcn_mfma_f32_16x16x32_bf16(al[kc], wh_hi[c][kc], acc[c], 0, 0, 0);
        acc[c] = __builtin_amdgcn_mfma_f32_16x16x32_bf16(ah[kc], wh_lo[c][kc], acc[c], 0, 0, 0);
      }
    }

    // convert this step's x to frags, then prefetch next step's x
    bf16x8 xh[2], xl[2];
    {
      float v[8];
      *(float4*)&v[0] = xa0; *(float4*)&v[4] = xa1;
      split8(v, xh[0], xl[0]);
    }
    {
      float v[8];
      *(float4*)&v[0] = xb0; *(float4*)&v[4] = xb1;
      split8(v, xh[1], xl[1]);
    }
    if (t + 1 < T_STEPS) {
      const float* xn = xp + IN_DIM;
      xa0 = *(const float4*)(xn);
      xa1 = *(const float4*)(xn + 4);
      if (g16 == 0) {
        xb0 = *(const float4*)(xn + 32);
        xb1 = *(const float4*)(xn + 36);
      }
      xp = xn;
    }

    // input projection: z += x @ w_ih^T
#pragma unroll
    for (int c = 0; c < 4; ++c) {
#pragma unroll
      for (int kc = 0; kc < 2; ++kc) {
        acc[c] = __builtin_amdgcn_mfma_f32_16x16x32_bf16(xh[kc], wi_hi[c][kc], acc[c], 0, 0, 0);
        acc[c] = __builtin_amdgcn_mfma_f32_16x16x32_bf16(xl[kc], wi_hi[c][kc], acc[c], 0, 0, 0);
        acc[c] = __builtin_amdgcn_mfma_f32_16x16x32_bf16(xh[kc], wi_lo[c][kc], acc[c], 0, 0, 0);
      }
    }

    // gates + state + fused classifier; write split h for next step
    const float wc = w_clf[t * 64 + n];
#pragma unroll
    for (int r = 0; r < 4; ++r) {
      const float zi = acc[0][r], zf = acc[1][r], zg = acc[2][r], zo = acc[3][r];
      cc[r] = sigm(zf) * cc[r] + sigm(zi) * tanh_fast(zg);
      const float h = sigm(zo) * tanh_fast(cc[r]);
      aclf[r] += h * wc;
      const int b = g16 * 4 + r;  // D row = batch
      ushort_t hh, hl;
      split1(h, hh, hl);
      const int idx = ((n >> 3) ^ (b & 7)) * 8 + (n & 7);
      hbuf[bw][0][b][idx] = hh;
      hbuf[bw][1][b][idx] = hl;
    }
    __syncthreads();
  }

  // ---- epilogue: reduce classifier partials over hidden dim ----
#pragma unroll
  for (int r = 0; r < 4; ++r) red[n][g16 * 4 + r] = aclf[r];
  __syncthreads();
  if (tid < 16) {
    float s = b_clf[0];
#pragma unroll 8
    for (int j = 0; j < 64; ++j) s += red[j][tid];
    out[blockIdx.x * 16 + tid] = s;
  }
}

extern "C" void kernel_launch(void* const* d_in, const int* in_sizes, int n_in,
                              void* d_out, int out_size, void* d_ws, size_t ws_size,
                              hipStream_t stream) {
  const float* x     = (const float*)d_in[0];
  const float* w_ih  = (const float*)d_in[1];
  const float* w_hh  = (const float*)d_in[2];
  const float* b_ih  = (const float*)d_in[3];
  const float* b_hh  = (const float*)d_in[4];
  const float* w_clf = (const float*)d_in[5];
  const float* b_clf = (const float*)d_in[6];
  float* out = (float*)d_out;

  lstm_mfma<<<256, 256, 0, stream>>>(x, w_ih, w_hh, b_ih, b_hh, w_clf, b_clf, out);
}